// Round 18
// baseline (29.532 us; speedup 1.0000x reference)
//
#include <hip/hip_runtime.h>

#define NN 62
#define FF 5
#define KC 4
#define CO 64
#define NSEL 31
#define NF 310
#define NBATCH 4096
#define TPB 512        // 8 waves, 2/SIMD, one block/CU
#define BPB 16         // 8 waves x 2 batches
#define XS_ST 24       // xs row stride elems (16B-aligned rows for b128 A-frag reads)
#define XS_BY 48
#define AD_ST 72
#define AD_BY 144
#define WT_BY 80
#define U_BY  144

typedef __bf16 bf16x8 __attribute__((ext_vector_type(8)));
typedef __bf16 bf16x4 __attribute__((ext_vector_type(4)));
typedef float f32x4 __attribute__((ext_vector_type(4)));
typedef float f32x2 __attribute__((ext_vector_type(2)));
typedef unsigned short u16x8 __attribute__((ext_vector_type(8)));

#define MFMA(A, B, C) __builtin_amdgcn_mfma_f32_16x16x32_bf16((A), (B), (C), 0, 0, 0)

static __device__ __forceinline__ unsigned short f2bf(float f) {
    __bf16 b = (__bf16)f;
    return __builtin_bit_cast(unsigned short, b);
}
static __device__ __forceinline__ float bf2f(unsigned short s) {
    return __uint_as_float(((unsigned)s) << 16);
}
static __device__ __forceinline__ bf16x8 ldfrag(const unsigned short* p, int byte_off) {
    return *(const bf16x8*)((const char*)p + byte_off);
}

// R17 skeleton minus: (a) atomic mask-build -> wave-local shfl-OR (kills 496 LDS
// atomics + one full-block barrier), (b) cheb setprio (measured-null SALU toggles
// on the serial critical path). Epilogue setprio + fcv hoist retained.

__global__ __launch_bounds__(TPB) void gnn_mfma(
    const float* __restrict__ x, const float* __restrict__ adj,
    const int* __restrict__ mask_idx,
    const float* __restrict__ gc_w, const float* __restrict__ gc_b,
    const float* __restrict__ gc1_w, const float* __restrict__ gc1_b,
    const float* __restrict__ gc2_w, const float* __restrict__ gc2_b,
    const float* __restrict__ fc1_w, const float* __restrict__ fc1_b,
    const float* __restrict__ fc2_w, const float* __restrict__ fc2_b,
    const float* __restrict__ cls_w, const float* __restrict__ cls_b,
    float* __restrict__ out)
{
    __shared__ __align__(16) unsigned short s_adjb[64 * AD_ST];      // 9216 B
    __shared__ __align__(16) unsigned short s_wt[3 * 64 * 40];       // 15360 B
    __shared__ __align__(16) unsigned short s_fc[64 * CO * 8];       // 65536 B, rows 62/63 zero
    __shared__ float s_bias[3][64];                                  // 768 B
    __shared__ float s_dis1[64];                                     // 256 B
    __shared__ float s_dis2[BPB][64];                                // 4096 B
    __shared__ unsigned s_mb[BPB][2];                                // 128 B
    __shared__ __align__(16) unsigned short s_ut[8][16 * AD_ST];     // 18432 B per-wave U^T
    __shared__ __align__(16) unsigned short s_xs[8 * 2 * 64 * XS_ST + 8]; // 49168 B
    // total 162960 B <= 163840

    const int t = threadIdx.x;
    const int w = t >> 6, lane = t & 63;
    const int g = lane >> 4, c = lane & 15;
    const int b0 = blockIdx.x * BPB;

    unsigned short* xsW0 = &s_xs[(w * 2 + 0) * 64 * XS_ST];
    unsigned short* xsW1 = &s_xs[(w * 2 + 1) * 64 * XS_ST];
    unsigned short* utW  = &s_ut[w][0];

    // ---- per-wave zeroing FIRST (overlaps staging global-load latency) ----
    {
        unsigned* z = (unsigned*)xsW0;
        #pragma unroll
        for (int i = 0; i < (64 * XS_ST) / 64; ++i) z[lane + i * 64] = 0u;
        unsigned* zu = (unsigned*)utW;
        #pragma unroll
        for (int i = 0; i < (16 * AD_ST / 2) / 64; ++i) zu[lane + i * 64] = 0u;
    }
    if (t < 8) s_xs[8 * 2 * 64 * XS_ST + t] = 0;

    // ---- wave-local mask build (shfl-OR; no atomics, no extra barrier) ----
    #pragma unroll
    for (int bi = 0; bi < 2; ++bi) {
        const int bb = w * 2 + bi;
        unsigned ulo = 0u, uhi = 0u;
        if (lane < NSEL) {
            int idx = mask_idx[(b0 + bb) * NSEL + lane];
            if (idx < 32) ulo = 1u << idx; else uhi = 1u << (idx - 32);
        }
        #pragma unroll
        for (int off = 32; off > 0; off >>= 1) {
            ulo |= __shfl_xor(ulo, off);
            uhi |= __shfl_xor(uhi, off);
        }
        if (lane == 0) { s_mb[bb][0] = ulo; s_mb[bb][1] = uhi; }
    }

    // ================= block-cooperative staging (division-free) =================
    for (int r = w; r < 64; r += 8) {                       // adj rows, lane = col
        float v = (r < NN && lane < NN) ? adj[r * NN + lane] : 0.0f;
        s_adjb[r * AD_ST + lane] = f2bf(v);
    }
    for (int i = t; i < 64 * 8; i += TPB) {                 // pad cols 64..71
        int r = i >> 3, cc = 64 + (i & 7);
        s_adjb[r * AD_ST + cc] = (unsigned short)0;
    }
    // wt: 192 (head,o) rows x 40 kf; thread handles 5 consecutive kf
    for (int row = w * 8 + (lane >> 3); row < 192; row += 64) {
        int head = row >> 6, o = row & 63;
        const float* wp = (head == 0) ? gc1_w : (head == 1) ? gc2_w : gc_w;
        int kf0 = (lane & 7) * 5;
        #pragma unroll
        for (int j = 0; j < 5; ++j) {
            int kf = kf0 + j;
            s_wt[row * 40 + kf] = f2bf((kf < KC * FF) ? wp[kf * CO + o] : 0.0f);
        }
    }
    for (int i = t; i < 64 * CO; i += TPB) {
        int r = i >> 6;
        u16x8 v;
        if (r < NN) {
            const float* f1p = fc1_w + i * 3;
            const float* f2p = fc2_w + i * 3;
            const float* fgp = cls_w + i * 2;
            v[0] = f2bf(f1p[0]); v[1] = f2bf(f1p[1]); v[2] = f2bf(f1p[2]);
            v[3] = f2bf(f2p[0]); v[4] = f2bf(f2p[1]); v[5] = f2bf(f2p[2]);
            v[6] = f2bf(fgp[0]); v[7] = f2bf(fgp[1]);
        } else {
            #pragma unroll
            for (int j = 0; j < 8; ++j) v[j] = (unsigned short)0;
        }
        *(u16x8*)&s_fc[i * 8] = v;
    }
    if (t < 192) {
        int head = t >> 6, o = t & 63;
        const float* bp = (head == 0) ? gc1_b : (head == 1) ? gc2_b : gc_b;
        s_bias[head][o] = bp[o];
    }
    __syncthreads();   // B1: staging + masks visible

    // ---- dis1/dis2 via MFMA on staged bf16 adj ----
    if (w < 4) {
        unsigned mlo = s_mb[c][0], mhi = s_mb[c][1];
        bf16x8 M0, M1;
        #pragma unroll
        for (int e = 0; e < 8; ++e) {
            int l = g * 8 + e;
            M0[e] = __builtin_bit_cast(__bf16, (unsigned short)(((mlo >> l) & 1u) ? 0x3F80 : 0));
            M1[e] = __builtin_bit_cast(__bf16, (unsigned short)(((mhi >> l) & 1u) ? 0x3F80 : 0));
        }
        bf16x8 A0 = ldfrag(s_adjb, (w * 16 + c) * AD_BY + g * 16);
        bf16x8 A1 = ldfrag(s_adjb, (w * 16 + c) * AD_BY + 64 + g * 16);
        f32x4 Cd = {0.f, 0.f, 0.f, 0.f};
        Cd = MFMA(A0, M0, Cd);
        Cd = MFMA(A1, M1, Cd);
        #pragma unroll
        for (int i = 0; i < 4; ++i) {
            int j = w * 16 + g * 4 + i;
            unsigned bit = (j < 32) ? ((mlo >> j) & 1u) : ((mhi >> (j - 32)) & 1u);
            float s = bit ? Cd[i] : 0.0f;
            s_dis2[c][j] = (s > 0.0f) ? rsqrtf(s) : 0.0f;
        }
    } else if (w == 4) {
        bf16x8 ones;
        #pragma unroll
        for (int e = 0; e < 8; ++e)
            ones[e] = __builtin_bit_cast(__bf16, (unsigned short)0x3F80);
        #pragma unroll
        for (int mt = 0; mt < 4; ++mt) {
            bf16x8 A0 = ldfrag(s_adjb, (mt * 16 + c) * AD_BY + g * 16);
            bf16x8 A1 = ldfrag(s_adjb, (mt * 16 + c) * AD_BY + 64 + g * 16);
            f32x4 Cd = {0.f, 0.f, 0.f, 0.f};
            Cd = MFMA(A0, ones, Cd);
            Cd = MFMA(A1, ones, Cd);
            if (c == 0) {
                #pragma unroll
                for (int i = 0; i < 4; ++i) {
                    float d = Cd[i];
                    s_dis1[mt * 16 + g * 4 + i] = (d > 0.0f) ? rsqrtf(d) : 0.0f;
                }
            }
        }
    }
    __syncthreads();   // B2 -- last barrier; waves independent from here

    bf16x8 adjA[4][2];
    #pragma unroll
    for (int mt = 0; mt < 4; ++mt)
        #pragma unroll
        for (int kf2 = 0; kf2 < 2; ++kf2)
            adjA[mt][kf2] = ldfrag(s_adjb, (mt * 16 + c) * AD_BY + kf2 * 64 + g * 16);

    const int f_c = (c < 5) ? c : (c < 10 ? c - 5 : 0);
    const int bbp0 = w * 2, bbp1 = w * 2 + 1;

    // ---- prefetch BOTH batches' x rows up front (named regs, rule-#20 safe) ----
    float xpre0[5], xpre1[5];
    {
        const float* xb0 = x + (size_t)(b0 + bbp0) * NF;
        const float* xb1 = x + (size_t)(b0 + bbp1) * NF;
        #pragma unroll
        for (int it = 0; it < 5; ++it) {
            int e = lane + it * 64;
            xpre0[it] = (e < NF) ? xb0[e] : 0.0f;
            xpre1[it] = (e < NF) ? xb1[e] : 0.0f;
        }
    }

    bf16x8 A1f[2][4], A2f[2][4];

    #pragma unroll
    for (int bi = 0; bi < 2; ++bi) {
        const int bb = w * 2 + bi;

        // ---- stage x0 from prefetched regs (path1 = x, path2 = x*m) ----
        const unsigned mlo = s_mb[bb][0], mhi = s_mb[bb][1];
        #pragma unroll
        for (int it = 0; it < 5; ++it) {
            int e = lane + it * 64;
            if (e < NF) {
                int n = e / 5, f = e - n * 5;
                float v = (bi == 0) ? xpre0[it] : xpre1[it];
                unsigned bit = (n < 32) ? ((mlo >> n) & 1u) : ((mhi >> (n - 32)) & 1u);
                xsW0[n * XS_ST + f] = f2bf(v);
                xsW1[n * XS_ST + f] = f2bf(bit ? v : 0.0f);
            }
        }

        // ---- per-lane dis selection ----
        float dsel[16];
        const float* dsp = (c < 5) ? s_dis1 : s_dis2[bb];
        #pragma unroll
        for (int mt = 0; mt < 4; ++mt)
            #pragma unroll
            for (int i = 0; i < 4; ++i)
                dsel[mt * 4 + i] = (c < 10) ? dsp[mt * 16 + g * 4 + i] : 0.0f;

        // ---- x0 fragments (C-layout: row = mt*16+g*4+i, col = c) ----
        const unsigned short* xsp = (c >= 5 && c < 10) ? xsW1 : xsW0;
        f32x4 xA[4];
        #pragma unroll
        for (int mt = 0; mt < 4; ++mt)
            #pragma unroll
            for (int i = 0; i < 4; ++i) {
                int r = mt * 16 + g * 4 + i;
                xA[mt][i] = (c < 10) ? bf2f(xsp[r * XS_ST + f_c]) : 0.0f;
            }

        // ---- U0 = dis .* x0 -> U^T[q=c][j], one b64 write per mt ----
        if (c < 10) {
            #pragma unroll
            for (int mt = 0; mt < 4; ++mt) {
                bf16x4 uv;
                uv[0] = (__bf16)(dsel[mt*4+0] * xA[mt][0]);
                uv[1] = (__bf16)(dsel[mt*4+1] * xA[mt][1]);
                uv[2] = (__bf16)(dsel[mt*4+2] * xA[mt][2]);
                uv[3] = (__bf16)(dsel[mt*4+3] * xA[mt][3]);
                *(bf16x4*)((char*)utW + c * U_BY + (mt * 16 + g * 4) * 2) = uv;
            }
        }

        // ---- Chebyshev k=1..3 (wave-private; independent MFMA pair) ----
        f32x4 x1f[4];
        #pragma unroll
        for (int k = 1; k <= 3; ++k) {
            const float cck = (k == 1) ? 1.0f : 2.0f;
            bf16x8 Uf0 = ldfrag(utW, c * U_BY + g * 16);
            bf16x8 Uf1 = ldfrag(utW, c * U_BY + 64 + g * 16);
            #pragma unroll
            for (int mt = 0; mt < 4; ++mt) {
                const f32x4 z = {0.f, 0.f, 0.f, 0.f};
                f32x4 Ca = MFMA(adjA[mt][0], Uf0, z);
                f32x4 Cb = MFMA(adjA[mt][1], Uf1, z);
                f32x4 Cv = Ca + Cb;
                f32x4 xn;
                #pragma unroll
                for (int i = 0; i < 4; ++i) {
                    float v = -cck * dsel[mt * 4 + i] * Cv[i];
                    if (k == 2) v -= xA[mt][i];
                    if (k == 3) v -= x1f[mt][i];
                    xn[i] = v;
                }
                if (c < 10) {
                    unsigned short* dst = (c < 5) ? xsW0 : xsW1;
                    #pragma unroll
                    for (int i = 0; i < 4; ++i)
                        dst[(mt * 16 + g * 4 + i) * XS_ST + k * 5 + f_c] = f2bf(xn[i]);
                    if (k < 3) {
                        bf16x4 uv;
                        uv[0] = (__bf16)(dsel[mt*4+0] * xn[0]);
                        uv[1] = (__bf16)(dsel[mt*4+1] * xn[1]);
                        uv[2] = (__bf16)(dsel[mt*4+2] * xn[2]);
                        uv[3] = (__bf16)(dsel[mt*4+3] * xn[3]);
                        *(bf16x4*)((char*)utW + c * U_BY + (mt * 16 + g * 4) * 2) = uv;
                    }
                }
                if (k == 1) x1f[mt] = xn;
            }
        }

        // ---- einsum A-frags for this batch ----
        #pragma unroll
        for (int mt = 0; mt < 4; ++mt) {
            A1f[bi][mt] = ldfrag(xsW0, (mt * 16 + c) * XS_BY + g * 16);
            A2f[bi][mt] = ldfrag(xsW1, (mt * 16 + c) * XS_BY + g * 16);
        }
    } // bi

    // ====== fused einsum + ReLU + FC: both batches per group, f32x2 tail ======
    f32x2 acc0[4], acc1[4];
    #pragma unroll
    for (int q = 0; q < 4; ++q) { acc0[q] = f32x2{0.f, 0.f}; acc1[q] = f32x2{0.f, 0.f}; }

    #pragma unroll
    for (int nt = 0; nt < 4; ++nt) {
        bf16x8 W1f = ldfrag(s_wt, (0 * 64 + nt * 16 + c) * WT_BY + g * 16);
        bf16x8 W2f = ldfrag(s_wt, (1 * 64 + nt * 16 + c) * WT_BY + g * 16);
        bf16x8 Wgf = ldfrag(s_wt, (2 * 64 + nt * 16 + c) * WT_BY + g * 16);
        const f32x2 bb12 = { s_bias[0][nt * 16 + c], s_bias[1][nt * 16 + c] };
        const float bbg = s_bias[2][nt * 16 + c];
        #pragma unroll
        for (int mt = 0; mt < 4; ++mt) {
            const f32x4 z = {0.f, 0.f, 0.f, 0.f};
            __builtin_amdgcn_s_setprio(1);
            f32x4 C1a = MFMA(A1f[0][mt], W1f, z);
            f32x4 C1b = MFMA(A1f[1][mt], W1f, z);
            f32x4 C2a = MFMA(A2f[0][mt], W2f, z);
            f32x4 C2b = MFMA(A2f[1][mt], W2f, z);
            f32x4 Cga = MFMA(A1f[0][mt], Wgf, z);
            f32x4 Cgb = MFMA(A1f[1][mt], Wgf, z);
            __builtin_amdgcn_s_setprio(0);
            // hoisted fcv reads: 4 independent b128 issues, one latency exposure
            const int rb = (mt * 16 + g * 4) * CO + nt * 16 + c;
            const u16x8 fcv0 = *(const u16x8*)((const char*)s_fc + ((rb + 0 * CO) << 4));
            const u16x8 fcv1 = *(const u16x8*)((const char*)s_fc + ((rb + 1 * CO) << 4));
            const u16x8 fcv2 = *(const u16x8*)((const char*)s_fc + ((rb + 2 * CO) << 4));
            const u16x8 fcv3 = *(const u16x8*)((const char*)s_fc + ((rb + 3 * CO) << 4));
            #pragma unroll
            for (int i = 0; i < 4; ++i) {
                const u16x8 fcv = (i == 0) ? fcv0 : (i == 1) ? fcv1 : (i == 2) ? fcv2 : fcv3;
                f32x2 f01  = { bf2f(fcv[0]), bf2f(fcv[1]) };
                f32x2 f2f0 = { bf2f(fcv[2]), bf2f(fcv[3]) };
                f32x2 f12  = { bf2f(fcv[4]), bf2f(fcv[5]) };
                f32x2 fg   = { bf2f(fcv[6]), bf2f(fcv[7]) };
                f32x2 h12a = f32x2{C1a[i], C2a[i]} + bb12;
                h12a.x = fmaxf(h12a.x, 0.f); h12a.y = fmaxf(h12a.y, 0.f);
                f32x2 h12b = f32x2{C1b[i], C2b[i]} + bb12;
                h12b.x = fmaxf(h12b.x, 0.f); h12b.y = fmaxf(h12b.y, 0.f);
                float hga = fmaxf(Cga[i] + bbg, 0.f);
                float hgb = fmaxf(Cgb[i] + bbg, 0.f);
                acc0[0] += f32x2{h12a.x, h12a.x} * f01;
                acc0[1] += f32x2{h12a.x, h12a.y} * f2f0;
                acc0[2] += f32x2{h12a.y, h12a.y} * f12;
                acc0[3] += f32x2{hga,    hga   } * fg;
                acc1[0] += f32x2{h12b.x, h12b.x} * f01;
                acc1[1] += f32x2{h12b.x, h12b.y} * f2f0;
                acc1[2] += f32x2{h12b.y, h12b.y} * f12;
                acc1[3] += f32x2{hgb,    hgb   } * fg;
            }
        }
    }

    // ---- wave reduction + output ----
    float red[16] = {
        acc0[0].x, acc0[0].y, acc0[1].x, acc0[1].y,
        acc0[2].x, acc0[2].y, acc0[3].x, acc0[3].y,
        acc1[0].x, acc1[0].y, acc1[1].x, acc1[1].y,
        acc1[2].x, acc1[2].y, acc1[3].x, acc1[3].y
    };
    #pragma unroll
    for (int off = 32; off > 0; off >>= 1)
        #pragma unroll
        for (int q = 0; q < 16; ++q)
            red[q] += __shfl_down(red[q], off);

    if (lane == 0) {
        #pragma unroll
        for (int bi = 0; bi < 2; ++bi) {
            const int b = b0 + w * 2 + bi;
            float l0 = red[bi * 8 + 0] + fc1_b[0];
            float l1 = red[bi * 8 + 1] + fc1_b[1];
            float l2 = red[bi * 8 + 2] + fc1_b[2];
            float m0 = red[bi * 8 + 3] + fc2_b[0];
            float m1 = red[bi * 8 + 4] + fc2_b[1];
            float m2 = red[bi * 8 + 5] + fc2_b[2];
            float g0 = red[bi * 8 + 6] + cls_b[0];
            float g1 = red[bi * 8 + 7] + cls_b[1];
            float mx = fmaxf(g0, g1);
            float e0 = expf(g0 - mx), e1 = expf(g1 - mx);
            float inv = 1.0f / (e0 + e1);
            float p0 = e0 * inv, p1 = e1 * inv;
            out[b * 3 + 0] = l0 * p0 + m0 * p1;
            out[b * 3 + 1] = l1 * p0 + m1 * p1;
            out[b * 3 + 2] = l2 * p0 + m2 * p1;
        }
    }
}

extern "C" void kernel_launch(void* const* d_in, const int* in_sizes, int n_in,
                              void* d_out, int out_size, void* d_ws, size_t ws_size,
                              hipStream_t stream) {
    const float* x      = (const float*)d_in[0];
    const float* adj    = (const float*)d_in[1];
    const int*   midx   = (const int*)  d_in[2];
    const float* gc_w   = (const float*)d_in[3];
    const float* gc_b   = (const float*)d_in[4];
    const float* gc1_w  = (const float*)d_in[5];
    const float* gc1_b  = (const float*)d_in[6];
    const float* gc2_w  = (const float*)d_in[7];
    const float* gc2_b  = (const float*)d_in[8];
    const float* fc1_w  = (const float*)d_in[9];
    const float* fc1_b  = (const float*)d_in[10];
    const float* fc2_w  = (const float*)d_in[11];
    const float* fc2_b  = (const float*)d_in[12];
    const float* cls_w  = (const float*)d_in[13];
    const float* cls_b  = (const float*)d_in[14];
    float* o = (float*)d_out;
    hipLaunchKernelGGL(gnn_mfma, dim3(NBATCH / BPB), dim3(TPB), 0, stream,
        x, adj, midx, gc_w, gc_b, gc1_w, gc1_b, gc2_w, gc2_b,
        fc1_w, fc1_b, fc2_w, fc2_b, cls_w, cls_b, o);
}

// Round 20
// 29.060 us; speedup vs baseline: 1.0162x; 1.0162x over previous
//
#include <hip/hip_runtime.h>

#define NN 62
#define FF 5
#define KC 4
#define CO 64
#define NSEL 31
#define NF 310
#define NBATCH 4096
#define TPB 512        // 8 waves, 2/SIMD, one block/CU
#define BPB 16         // 8 waves x 2 batches
#define XS_ST 24       // xs row stride elems (16B-aligned rows for b128 A-frag reads)
#define XS_BY 48
#define AD_ST 72
#define AD_BY 144
#define WT_BY 80
#define U_BY  144
#define XS_WAVE (2 * 64 * XS_ST + 8)   // per-wave xs region incl. PRIVATE 16B tail pad

typedef __bf16 bf16x8 __attribute__((ext_vector_type(8)));
typedef __bf16 bf16x4 __attribute__((ext_vector_type(4)));
typedef float f32x4 __attribute__((ext_vector_type(4)));
typedef float f32x2 __attribute__((ext_vector_type(2)));
typedef unsigned short u16x8 __attribute__((ext_vector_type(8)));

#define MFMA(A, B, C) __builtin_amdgcn_mfma_f32_16x16x32_bf16((A), (B), (C), 0, 0, 0)

static __device__ __forceinline__ unsigned short f2bf(float f) {
    __bf16 b = (__bf16)f;
    return __builtin_bit_cast(unsigned short, b);
}
static __device__ __forceinline__ float bf2f(unsigned short s) {
    return __uint_as_float(((unsigned)s) << 16);
}
static __device__ __forceinline__ bf16x8 ldfrag(const unsigned short* p, int byte_off) {
    return *(const bf16x8*)((const char*)p + byte_off);
}

// R17 structure (best measured 28.95us) + RACE FIX: per-wave xs tail pad.
// R19 showed a scheduling-dependent post-timing divergence; the only inter-wave
// dataflow after the last barrier was the row-63 g=3 A-frag b128 read spilling
// 16B past xsW1 into the NEXT wave's live xsW0. Each wave's region now carries
// its own zeroed 16B pad, so that read is wave-private and constant.

__global__ __launch_bounds__(TPB) void gnn_mfma(
    const float* __restrict__ x, const float* __restrict__ adj,
    const int* __restrict__ mask_idx,
    const float* __restrict__ gc_w, const float* __restrict__ gc_b,
    const float* __restrict__ gc1_w, const float* __restrict__ gc1_b,
    const float* __restrict__ gc2_w, const float* __restrict__ gc2_b,
    const float* __restrict__ fc1_w, const float* __restrict__ fc1_b,
    const float* __restrict__ fc2_w, const float* __restrict__ fc2_b,
    const float* __restrict__ cls_w, const float* __restrict__ cls_b,
    float* __restrict__ out)
{
    __shared__ __align__(16) unsigned short s_adjb[64 * AD_ST];      // 9216 B
    __shared__ __align__(16) unsigned short s_wt[3 * 64 * 40];       // 15360 B
    __shared__ __align__(16) unsigned short s_fc[64 * CO * 8];       // 65536 B, rows 62/63 zero
    __shared__ float s_bias[3][64];                                  // 768 B
    __shared__ float s_dis1[64];                                     // 256 B
    __shared__ float s_dis2[BPB][64];                                // 4096 B
    __shared__ unsigned s_mb[BPB][2];                                // 128 B
    __shared__ __align__(16) unsigned short s_ut[8][16 * AD_ST];     // 18432 B per-wave U^T
    __shared__ __align__(16) unsigned short s_xs[8][XS_WAVE];        // 49280 B (per-wave pad)
    // total 163072 B <= 163840

    const int t = threadIdx.x;
    const int w = t >> 6, lane = t & 63;
    const int g = lane >> 4, c = lane & 15;
    const int b0 = blockIdx.x * BPB;

    unsigned short* xsW0 = &s_xs[w][0];
    unsigned short* xsW1 = &s_xs[w][64 * XS_ST];
    unsigned short* utW  = &s_ut[w][0];

    // ---- per-wave zeroing FIRST (overlaps staging global-load latency) ----
    {
        unsigned* z = (unsigned*)xsW0;
        #pragma unroll
        for (int i = 0; i < (2 * 64 * XS_ST / 2) / 64; ++i) z[lane + i * 64] = 0u;
        if (lane < 4) z[2 * 64 * XS_ST / 2 + lane] = 0u;   // private 16B tail pad
        unsigned* zu = (unsigned*)utW;
        #pragma unroll
        for (int i = 0; i < (16 * AD_ST / 2) / 64; ++i) zu[lane + i * 64] = 0u;
    }

    // ================= block-cooperative staging (division-free) =================
    for (int r = w; r < 64; r += 8) {                       // adj rows, lane = col
        float v = (r < NN && lane < NN) ? adj[r * NN + lane] : 0.0f;
        s_adjb[r * AD_ST + lane] = f2bf(v);
    }
    for (int i = t; i < 64 * 8; i += TPB) {                 // pad cols 64..71
        int r = i >> 3, cc = 64 + (i & 7);
        s_adjb[r * AD_ST + cc] = (unsigned short)0;
    }
    // wt: 192 (head,o) rows x 40 kf; thread handles 5 consecutive kf
    for (int row = w * 8 + (lane >> 3); row < 192; row += 64) {
        int head = row >> 6, o = row & 63;
        const float* wp = (head == 0) ? gc1_w : (head == 1) ? gc2_w : gc_w;
        int kf0 = (lane & 7) * 5;
        #pragma unroll
        for (int j = 0; j < 5; ++j) {
            int kf = kf0 + j;
            s_wt[row * 40 + kf] = f2bf((kf < KC * FF) ? wp[kf * CO + o] : 0.0f);
        }
    }
    for (int i = t; i < 64 * CO; i += TPB) {
        int r = i >> 6;
        u16x8 v;
        if (r < NN) {
            const float* f1p = fc1_w + i * 3;
            const float* f2p = fc2_w + i * 3;
            const float* fgp = cls_w + i * 2;
            v[0] = f2bf(f1p[0]); v[1] = f2bf(f1p[1]); v[2] = f2bf(f1p[2]);
            v[3] = f2bf(f2p[0]); v[4] = f2bf(f2p[1]); v[5] = f2bf(f2p[2]);
            v[6] = f2bf(fgp[0]); v[7] = f2bf(fgp[1]);
        } else {
            #pragma unroll
            for (int j = 0; j < 8; ++j) v[j] = (unsigned short)0;
        }
        *(u16x8*)&s_fc[i * 8] = v;
    }
    if (t < 192) {
        int head = t >> 6, o = t & 63;
        const float* bp = (head == 0) ? gc1_b : (head == 1) ? gc2_b : gc_b;
        s_bias[head][o] = bp[o];
    }
    if (t < BPB * 2) ((unsigned*)s_mb)[t] = 0u;
    __syncthreads();   // B1

    for (int i = t; i < BPB * NSEL; i += TPB) {
        int bt = i / NSEL, s = i - bt * NSEL;
        int idx = mask_idx[(b0 + bt) * NSEL + s];
        atomicOr(&s_mb[bt][idx >> 5], 1u << (idx & 31));
    }
    __syncthreads();   // B2

    // ---- dis1/dis2 via MFMA on staged bf16 adj ----
    if (w < 4) {
        unsigned mlo = s_mb[c][0], mhi = s_mb[c][1];
        bf16x8 M0, M1;
        #pragma unroll
        for (int e = 0; e < 8; ++e) {
            int l = g * 8 + e;
            M0[e] = __builtin_bit_cast(__bf16, (unsigned short)(((mlo >> l) & 1u) ? 0x3F80 : 0));
            M1[e] = __builtin_bit_cast(__bf16, (unsigned short)(((mhi >> l) & 1u) ? 0x3F80 : 0));
        }
        bf16x8 A0 = ldfrag(s_adjb, (w * 16 + c) * AD_BY + g * 16);
        bf16x8 A1 = ldfrag(s_adjb, (w * 16 + c) * AD_BY + 64 + g * 16);
        f32x4 Cd = {0.f, 0.f, 0.f, 0.f};
        Cd = MFMA(A0, M0, Cd);
        Cd = MFMA(A1, M1, Cd);
        #pragma unroll
        for (int i = 0; i < 4; ++i) {
            int j = w * 16 + g * 4 + i;
            unsigned bit = (j < 32) ? ((mlo >> j) & 1u) : ((mhi >> (j - 32)) & 1u);
            float s = bit ? Cd[i] : 0.0f;
            s_dis2[c][j] = (s > 0.0f) ? rsqrtf(s) : 0.0f;
        }
    } else if (w == 4) {
        bf16x8 ones;
        #pragma unroll
        for (int e = 0; e < 8; ++e)
            ones[e] = __builtin_bit_cast(__bf16, (unsigned short)0x3F80);
        #pragma unroll
        for (int mt = 0; mt < 4; ++mt) {
            bf16x8 A0 = ldfrag(s_adjb, (mt * 16 + c) * AD_BY + g * 16);
            bf16x8 A1 = ldfrag(s_adjb, (mt * 16 + c) * AD_BY + 64 + g * 16);
            f32x4 Cd = {0.f, 0.f, 0.f, 0.f};
            Cd = MFMA(A0, ones, Cd);
            Cd = MFMA(A1, ones, Cd);
            if (c == 0) {
                #pragma unroll
                for (int i = 0; i < 4; ++i) {
                    float d = Cd[i];
                    s_dis1[mt * 16 + g * 4 + i] = (d > 0.0f) ? rsqrtf(d) : 0.0f;
                }
            }
        }
    }
    __syncthreads();   // B3 -- last barrier; waves independent from here

    bf16x8 adjA[4][2];
    #pragma unroll
    for (int mt = 0; mt < 4; ++mt)
        #pragma unroll
        for (int kf2 = 0; kf2 < 2; ++kf2)
            adjA[mt][kf2] = ldfrag(s_adjb, (mt * 16 + c) * AD_BY + kf2 * 64 + g * 16);

    const int f_c = (c < 5) ? c : (c < 10 ? c - 5 : 0);
    const int bbp0 = w * 2, bbp1 = w * 2 + 1;

    // ---- prefetch BOTH batches' x rows up front (named regs, rule-#20 safe) ----
    float xpre0[5], xpre1[5];
    {
        const float* xb0 = x + (size_t)(b0 + bbp0) * NF;
        const float* xb1 = x + (size_t)(b0 + bbp1) * NF;
        #pragma unroll
        for (int it = 0; it < 5; ++it) {
            int e = lane + it * 64;
            xpre0[it] = (e < NF) ? xb0[e] : 0.0f;
            xpre1[it] = (e < NF) ? xb1[e] : 0.0f;
        }
    }

    bf16x8 A1f[2][4], A2f[2][4];

    #pragma unroll
    for (int bi = 0; bi < 2; ++bi) {
        const int bb = w * 2 + bi;

        // ---- stage x0 from prefetched regs (path1 = x, path2 = x*m) ----
        const unsigned mlo = s_mb[bb][0], mhi = s_mb[bb][1];
        #pragma unroll
        for (int it = 0; it < 5; ++it) {
            int e = lane + it * 64;
            if (e < NF) {
                int n = e / 5, f = e - n * 5;
                float v = (bi == 0) ? xpre0[it] : xpre1[it];
                unsigned bit = (n < 32) ? ((mlo >> n) & 1u) : ((mhi >> (n - 32)) & 1u);
                xsW0[n * XS_ST + f] = f2bf(v);
                xsW1[n * XS_ST + f] = f2bf(bit ? v : 0.0f);
            }
        }

        // ---- per-lane dis selection ----
        float dsel[16];
        const float* dsp = (c < 5) ? s_dis1 : s_dis2[bb];
        #pragma unroll
        for (int mt = 0; mt < 4; ++mt)
            #pragma unroll
            for (int i = 0; i < 4; ++i)
                dsel[mt * 4 + i] = (c < 10) ? dsp[mt * 16 + g * 4 + i] : 0.0f;

        // ---- x0 fragments (C-layout: row = mt*16+g*4+i, col = c) ----
        const unsigned short* xsp = (c >= 5 && c < 10) ? xsW1 : xsW0;
        f32x4 xA[4];
        #pragma unroll
        for (int mt = 0; mt < 4; ++mt)
            #pragma unroll
            for (int i = 0; i < 4; ++i) {
                int r = mt * 16 + g * 4 + i;
                xA[mt][i] = (c < 10) ? bf2f(xsp[r * XS_ST + f_c]) : 0.0f;
            }

        // ---- U0 = dis .* x0 -> U^T[q=c][j], one b64 write per mt ----
        if (c < 10) {
            #pragma unroll
            for (int mt = 0; mt < 4; ++mt) {
                bf16x4 uv;
                uv[0] = (__bf16)(dsel[mt*4+0] * xA[mt][0]);
                uv[1] = (__bf16)(dsel[mt*4+1] * xA[mt][1]);
                uv[2] = (__bf16)(dsel[mt*4+2] * xA[mt][2]);
                uv[3] = (__bf16)(dsel[mt*4+3] * xA[mt][3]);
                *(bf16x4*)((char*)utW + c * U_BY + (mt * 16 + g * 4) * 2) = uv;
            }
        }

        // ---- Chebyshev k=1..3 (wave-private; setprio around MFMA pair) ----
        f32x4 x1f[4];
        #pragma unroll
        for (int k = 1; k <= 3; ++k) {
            const float cck = (k == 1) ? 1.0f : 2.0f;
            bf16x8 Uf0 = ldfrag(utW, c * U_BY + g * 16);
            bf16x8 Uf1 = ldfrag(utW, c * U_BY + 64 + g * 16);
            #pragma unroll
            for (int mt = 0; mt < 4; ++mt) {
                const f32x4 z = {0.f, 0.f, 0.f, 0.f};
                __builtin_amdgcn_s_setprio(1);
                f32x4 Ca = MFMA(adjA[mt][0], Uf0, z);
                f32x4 Cb = MFMA(adjA[mt][1], Uf1, z);
                __builtin_amdgcn_s_setprio(0);
                f32x4 Cv = Ca + Cb;
                f32x4 xn;
                #pragma unroll
                for (int i = 0; i < 4; ++i) {
                    float v = -cck * dsel[mt * 4 + i] * Cv[i];
                    if (k == 2) v -= xA[mt][i];
                    if (k == 3) v -= x1f[mt][i];
                    xn[i] = v;
                }
                if (c < 10) {
                    unsigned short* dst = (c < 5) ? xsW0 : xsW1;
                    #pragma unroll
                    for (int i = 0; i < 4; ++i)
                        dst[(mt * 16 + g * 4 + i) * XS_ST + k * 5 + f_c] = f2bf(xn[i]);
                    if (k < 3) {
                        bf16x4 uv;
                        uv[0] = (__bf16)(dsel[mt*4+0] * xn[0]);
                        uv[1] = (__bf16)(dsel[mt*4+1] * xn[1]);
                        uv[2] = (__bf16)(dsel[mt*4+2] * xn[2]);
                        uv[3] = (__bf16)(dsel[mt*4+3] * xn[3]);
                        *(bf16x4*)((char*)utW + c * U_BY + (mt * 16 + g * 4) * 2) = uv;
                    }
                }
                if (k == 1) x1f[mt] = xn;
            }
        }

        // ---- einsum A-frags for this batch (row-63 g=3 read lands in OWN pad) ----
        #pragma unroll
        for (int mt = 0; mt < 4; ++mt) {
            A1f[bi][mt] = ldfrag(xsW0, (mt * 16 + c) * XS_BY + g * 16);
            A2f[bi][mt] = ldfrag(xsW1, (mt * 16 + c) * XS_BY + g * 16);
        }
    } // bi

    // ====== fused einsum + ReLU + FC: both batches per group, f32x2 tail ======
    f32x2 acc0[4], acc1[4];
    #pragma unroll
    for (int q = 0; q < 4; ++q) { acc0[q] = f32x2{0.f, 0.f}; acc1[q] = f32x2{0.f, 0.f}; }

    #pragma unroll
    for (int nt = 0; nt < 4; ++nt) {
        bf16x8 W1f = ldfrag(s_wt, (0 * 64 + nt * 16 + c) * WT_BY + g * 16);
        bf16x8 W2f = ldfrag(s_wt, (1 * 64 + nt * 16 + c) * WT_BY + g * 16);
        bf16x8 Wgf = ldfrag(s_wt, (2 * 64 + nt * 16 + c) * WT_BY + g * 16);
        const f32x2 bb12 = { s_bias[0][nt * 16 + c], s_bias[1][nt * 16 + c] };
        const float bbg = s_bias[2][nt * 16 + c];
        #pragma unroll
        for (int mt = 0; mt < 4; ++mt) {
            const f32x4 z = {0.f, 0.f, 0.f, 0.f};
            __builtin_amdgcn_s_setprio(1);
            f32x4 C1a = MFMA(A1f[0][mt], W1f, z);
            f32x4 C1b = MFMA(A1f[1][mt], W1f, z);
            f32x4 C2a = MFMA(A2f[0][mt], W2f, z);
            f32x4 C2b = MFMA(A2f[1][mt], W2f, z);
            f32x4 Cga = MFMA(A1f[0][mt], Wgf, z);
            f32x4 Cgb = MFMA(A1f[1][mt], Wgf, z);
            __builtin_amdgcn_s_setprio(0);
            // hoisted fcv reads: 4 independent b128 issues, one latency exposure
            const int rb = (mt * 16 + g * 4) * CO + nt * 16 + c;
            const u16x8 fcv0 = *(const u16x8*)((const char*)s_fc + ((rb + 0 * CO) << 4));
            const u16x8 fcv1 = *(const u16x8*)((const char*)s_fc + ((rb + 1 * CO) << 4));
            const u16x8 fcv2 = *(const u16x8*)((const char*)s_fc + ((rb + 2 * CO) << 4));
            const u16x8 fcv3 = *(const u16x8*)((const char*)s_fc + ((rb + 3 * CO) << 4));
            #pragma unroll
            for (int i = 0; i < 4; ++i) {
                const u16x8 fcv = (i == 0) ? fcv0 : (i == 1) ? fcv1 : (i == 2) ? fcv2 : fcv3;
                f32x2 f01  = { bf2f(fcv[0]), bf2f(fcv[1]) };
                f32x2 f2f0 = { bf2f(fcv[2]), bf2f(fcv[3]) };
                f32x2 f12  = { bf2f(fcv[4]), bf2f(fcv[5]) };
                f32x2 fg   = { bf2f(fcv[6]), bf2f(fcv[7]) };
                f32x2 h12a = f32x2{C1a[i], C2a[i]} + bb12;
                h12a.x = fmaxf(h12a.x, 0.f); h12a.y = fmaxf(h12a.y, 0.f);
                f32x2 h12b = f32x2{C1b[i], C2b[i]} + bb12;
                h12b.x = fmaxf(h12b.x, 0.f); h12b.y = fmaxf(h12b.y, 0.f);
                float hga = fmaxf(Cga[i] + bbg, 0.f);
                float hgb = fmaxf(Cgb[i] + bbg, 0.f);
                acc0[0] += f32x2{h12a.x, h12a.x} * f01;
                acc0[1] += f32x2{h12a.x, h12a.y} * f2f0;
                acc0[2] += f32x2{h12a.y, h12a.y} * f12;
                acc0[3] += f32x2{hga,    hga   } * fg;
                acc1[0] += f32x2{h12b.x, h12b.x} * f01;
                acc1[1] += f32x2{h12b.x, h12b.y} * f2f0;
                acc1[2] += f32x2{h12b.y, h12b.y} * f12;
                acc1[3] += f32x2{hgb,    hgb   } * fg;
            }
        }
    }

    // ---- wave reduction + output ----
    float red[16] = {
        acc0[0].x, acc0[0].y, acc0[1].x, acc0[1].y,
        acc0[2].x, acc0[2].y, acc0[3].x, acc0[3].y,
        acc1[0].x, acc1[0].y, acc1[1].x, acc1[1].y,
        acc1[2].x, acc1[2].y, acc1[3].x, acc1[3].y
    };
    #pragma unroll
    for (int off = 32; off > 0; off >>= 1)
        #pragma unroll
        for (int q = 0; q < 16; ++q)
            red[q] += __shfl_down(red[q], off);

    if (lane == 0) {
        #pragma unroll
        for (int bi = 0; bi < 2; ++bi) {
            const int b = b0 + w * 2 + bi;
            float l0 = red[bi * 8 + 0] + fc1_b[0];
            float l1 = red[bi * 8 + 1] + fc1_b[1];
            float l2 = red[bi * 8 + 2] + fc1_b[2];
            float m0 = red[bi * 8 + 3] + fc2_b[0];
            float m1 = red[bi * 8 + 4] + fc2_b[1];
            float m2 = red[bi * 8 + 5] + fc2_b[2];
            float g0 = red[bi * 8 + 6] + cls_b[0];
            float g1 = red[bi * 8 + 7] + cls_b[1];
            float mx = fmaxf(g0, g1);
            float e0 = expf(g0 - mx), e1 = expf(g1 - mx);
            float inv = 1.0f / (e0 + e1);
            float p0 = e0 * inv, p1 = e1 * inv;
            out[b * 3 + 0] = l0 * p0 + m0 * p1;
            out[b * 3 + 1] = l1 * p0 + m1 * p1;
            out[b * 3 + 2] = l2 * p0 + m2 * p1;
        }
    }
}

extern "C" void kernel_launch(void* const* d_in, const int* in_sizes, int n_in,
                              void* d_out, int out_size, void* d_ws, size_t ws_size,
                              hipStream_t stream) {
    const float* x      = (const float*)d_in[0];
    const float* adj    = (const float*)d_in[1];
    const int*   midx   = (const int*)  d_in[2];
    const float* gc_w   = (const float*)d_in[3];
    const float* gc_b   = (const float*)d_in[4];
    const float* gc1_w  = (const float*)d_in[5];
    const float* gc1_b  = (const float*)d_in[6];
    const float* gc2_w  = (const float*)d_in[7];
    const float* gc2_b  = (const float*)d_in[8];
    const float* fc1_w  = (const float*)d_in[9];
    const float* fc1_b  = (const float*)d_in[10];
    const float* fc2_w  = (const float*)d_in[11];
    const float* fc2_b  = (const float*)d_in[12];
    const float* cls_w  = (const float*)d_in[13];
    const float* cls_b  = (const float*)d_in[14];
    float* o = (float*)d_out;
    hipLaunchKernelGGL(gnn_mfma, dim3(NBATCH / BPB), dim3(TPB), 0, stream,
        x, adj, midx, gc_w, gc_b, gc1_w, gc1_b, gc2_w, gc2_b,
        fc1_w, fc1_b, fc2_w, fc2_b, cls_w, cls_b, o);
}